// Round 2
// baseline (1289.847 us; speedup 1.0000x reference)
//
#include <hip/hip_runtime.h>
#include <math.h>

#define N_NODES 100000
#define DIM 64
#define NUM_LAYER 3
#define BATCH 4096
#define REG_WEIGHT 1e-4f

// Large scratch as device globals — no dependence on ws_size (round-1 crash
// hypothesis: d_ws smaller than the ~55 MB my round-0 layout assumed).
__device__ float g_h[2][(size_t)N_NODES * DIM];   // ping-pong h buffers, 51.2 MB
__device__ float g_sums[(size_t)3 * BATCH * DIM]; // sampled-row accumulators
__device__ float g_deg[N_NODES];                  // degree -> dinv in place
__device__ float g_scalars[2];                    // softplus-sum, reg-sum

// ---- zero-fill helper (grid-stride) ----
__global__ void zero_f32(float* __restrict__ p, size_t n) {
    size_t i = (size_t)blockIdx.x * blockDim.x + threadIdx.x;
    size_t stride = (size_t)gridDim.x * blockDim.x;
    for (; i < n; i += stride) p[i] = 0.0f;
}

// ---- zero everything needed per call ----
__global__ void zero_all() {
    size_t i = (size_t)blockIdx.x * blockDim.x + threadIdx.x;
    size_t stride = (size_t)gridDim.x * blockDim.x;
    for (size_t k = i; k < (size_t)3 * BATCH * DIM; k += stride) g_sums[k] = 0.0f;
    for (size_t k = i; k < N_NODES; k += stride) g_deg[k] = 0.0f;
    if (i == 0) { g_scalars[0] = 0.0f; g_scalars[1] = 0.0f; }
}

// ---- degree count: one thread per edge ----
__global__ void count_deg(const int* __restrict__ dst, int E) {
    int e = blockIdx.x * blockDim.x + threadIdx.x;
    if (e < E) atomicAdd(&g_deg[dst[e]], 1.0f);
}

// ---- dinv in place ----
__global__ void make_dinv() {
    int v = blockIdx.x * blockDim.x + threadIdx.x;
    if (v < N_NODES) {
        float d = g_deg[v];
        g_deg[v] = (d > 0.0f) ? rsqrtf(d) : 0.0f;
    }
}

// ---- scatter one propagation layer: one wave (64 lanes) per edge, lane = dim ----
__global__ void scatter_layer(const float* __restrict__ h, const int* __restrict__ src,
                              const int* __restrict__ dst, float* __restrict__ hn, int E) {
    int wid  = (blockIdx.x * blockDim.x + threadIdx.x) >> 6;
    int lane = threadIdx.x & 63;
    if (wid >= E) return;
    int s = src[wid];
    int d = dst[wid];
    float adj = g_deg[s] * g_deg[d];
    float v = h[(size_t)s * DIM + lane] * adj;
    atomicAdd(&hn[(size_t)d * DIM + lane], v);
}

// ---- gather sampled rows into per-sample accumulators: wave per (which,sample) ----
__global__ void gather_acc(const float* __restrict__ h,
                           const int* __restrict__ users, const int* __restrict__ pos,
                           const int* __restrict__ neg) {
    int wid  = (blockIdx.x * blockDim.x + threadIdx.x) >> 6;
    int lane = threadIdx.x & 63;
    if (wid >= 3 * BATCH) return;
    int which = wid / BATCH;
    int i     = wid - which * BATCH;
    const int* idx = (which == 0) ? users : ((which == 1) ? pos : neg);
    int node = idx[i];
    g_sums[(size_t)wid * DIM + lane] += h[(size_t)node * DIM + lane];
}

// ---- per-sample scores + reg partials, wave-64 reduce, atomic into 2 scalars ----
__global__ void score_reduce(const float* __restrict__ emb,
                             const int* __restrict__ users, const int* __restrict__ pos,
                             const int* __restrict__ neg) {
    int wid  = (blockIdx.x * blockDim.x + threadIdx.x) >> 6;
    int lane = threadIdx.x & 63;
    if (wid >= BATCH) return;
    float u = 0.25f * g_sums[(size_t)wid * DIM + lane];
    float p = 0.25f * g_sums[(size_t)(BATCH + wid) * DIM + lane];
    float n = 0.25f * g_sums[(size_t)(2 * BATCH + wid) * DIM + lane];
    float ps = u * p;
    float ns = u * n;
    float u0 = emb[(size_t)users[wid] * DIM + lane];
    float p0 = emb[(size_t)pos[wid]   * DIM + lane];
    float n0 = emb[(size_t)neg[wid]   * DIM + lane];
    float rg = u0 * u0 + p0 * p0 + n0 * n0;
    #pragma unroll
    for (int off = 32; off > 0; off >>= 1) {
        ps += __shfl_down(ps, off);
        ns += __shfl_down(ns, off);
        rg += __shfl_down(rg, off);
    }
    if (lane == 0) {
        float x  = ns - ps;
        float sp = fmaxf(x, 0.0f) + log1pf(expf(-fabsf(x)));  // stable softplus
        atomicAdd(&g_scalars[0], sp);
        atomicAdd(&g_scalars[1], rg);
    }
}

// ---- write the 3 outputs ----
__global__ void finalize(float* __restrict__ out) {
    float loss_emb = g_scalars[0] / (float)BATCH;
    float reg      = 0.5f * g_scalars[1] / (float)BATCH * REG_WEIGHT;
    out[0] = loss_emb + reg;
    out[1] = loss_emb;
    out[2] = reg;
}

extern "C" void kernel_launch(void* const* d_in, const int* in_sizes, int n_in,
                              void* d_out, int out_size, void* d_ws, size_t ws_size,
                              hipStream_t stream) {
    const float* emb   = (const float*)d_in[0];
    const int*   src   = (const int*)d_in[1];
    const int*   dst   = (const int*)d_in[2];
    const int*   users = (const int*)d_in[3];
    const int*   pos   = (const int*)d_in[4];
    const int*   neg   = (const int*)d_in[5];
    const int E = in_sizes[1];
    float* out = (float*)d_out;

    float* h_a;  hipGetSymbolAddress((void**)&h_a, HIP_SYMBOL(g_h));
    float* h_b = h_a + (size_t)N_NODES * DIM;

    zero_all<<<1024, 256, 0, stream>>>();
    count_deg<<<(E + 255) / 256, 256, 0, stream>>>(dst, E);
    make_dinv<<<(N_NODES + 255) / 256, 256, 0, stream>>>();

    // layer 0 contribution (emb itself)
    gather_acc<<<(3 * BATCH * 64 + 255) / 256, 256, 0, stream>>>(emb, users, pos, neg);

    const float* hc = emb;
    float* bufs[2] = {h_a, h_b};
    for (int l = 0; l < NUM_LAYER; ++l) {
        float* hn = bufs[l & 1];
        zero_f32<<<2048, 256, 0, stream>>>(hn, (size_t)N_NODES * DIM);
        long long threads = (long long)E * 64;
        scatter_layer<<<(int)((threads + 255) / 256), 256, 0, stream>>>(hc, src, dst, hn, E);
        gather_acc<<<(3 * BATCH * 64 + 255) / 256, 256, 0, stream>>>(hn, users, pos, neg);
        hc = hn;
    }

    score_reduce<<<(BATCH * 64 + 255) / 256, 256, 0, stream>>>(emb, users, pos, neg);
    finalize<<<1, 1, 0, stream>>>(out);
}

// Round 3
// 586.898 us; speedup vs baseline: 2.1977x; 2.1977x over previous
//
#include <hip/hip_runtime.h>
#include <math.h>

#define N_NODES 100000
#define DIM 64
#define NUM_LAYER 3
#define BATCH 4096
#define REG_WEIGHT 1e-4f
#define SCAN_BLOCKS ((N_NODES + 255) / 256)   // 391

// All scratch as device globals (ws_size unknown; this passed in R2).
__device__ float g_h[2][(size_t)N_NODES * DIM];    // ping-pong h buffers, 51.2 MB
__device__ float g_sums[(size_t)3 * BATCH * DIM];  // sampled-row accumulators
__device__ int   g_cnt[N_NODES];                   // in-degree counts
__device__ int   g_fill[N_NODES];                  // CSR fill cursors
__device__ int   g_row_ptr[N_NODES + 1];           // CSR row offsets (by dst)
__device__ int   g_partials[SCAN_BLOCKS];          // scan partials
__device__ float g_dinv[N_NODES];                  // deg^-0.5
__device__ int   g_csr_src[1280000];               // CSR column (src) indices
__device__ float g_csr_w[1280000];                 // CSR edge weights
__device__ float g_scalars[2];                     // softplus-sum, reg-sum

// ---- zero the small per-call state ----
__global__ void zero_small() {
    size_t i = (size_t)blockIdx.x * blockDim.x + threadIdx.x;
    size_t stride = (size_t)gridDim.x * blockDim.x;
    for (size_t k = i; k < (size_t)3 * BATCH * DIM; k += stride) g_sums[k] = 0.0f;
    for (size_t k = i; k < N_NODES; k += stride) { g_cnt[k] = 0; g_fill[k] = 0; }
    if (i == 0) { g_scalars[0] = 0.0f; g_scalars[1] = 0.0f; }
}

// ---- degree count (int atomics) ----
__global__ void count_deg(const int* __restrict__ dst, int E) {
    int e = blockIdx.x * blockDim.x + threadIdx.x;
    if (e < E) atomicAdd(&g_cnt[dst[e]], 1);
}

// ---- dinv from counts ----
__global__ void make_dinv() {
    int v = blockIdx.x * blockDim.x + threadIdx.x;
    if (v < N_NODES) {
        int c = g_cnt[v];
        g_dinv[v] = (c > 0) ? rsqrtf((float)c) : 0.0f;
    }
}

// ---- exclusive scan of g_cnt -> g_row_ptr, 3 phases ----
__global__ void scan_blocks() {
    __shared__ int sm[256];
    int i = blockIdx.x * 256 + threadIdx.x;
    int v = (i < N_NODES) ? g_cnt[i] : 0;
    sm[threadIdx.x] = v;
    __syncthreads();
    for (int off = 1; off < 256; off <<= 1) {
        int t = (threadIdx.x >= off) ? sm[threadIdx.x - off] : 0;
        __syncthreads();
        sm[threadIdx.x] += t;
        __syncthreads();
    }
    if (i < N_NODES) g_row_ptr[i] = sm[threadIdx.x] - v;  // exclusive
    if (threadIdx.x == 255) g_partials[blockIdx.x] = sm[255];
}

__global__ void scan_partials(int E) {
    if (threadIdx.x == 0 && blockIdx.x == 0) {
        int run = 0;
        for (int b = 0; b < SCAN_BLOCKS; ++b) { int t = g_partials[b]; g_partials[b] = run; run += t; }
        g_row_ptr[N_NODES] = E;
    }
}

__global__ void scan_add() {
    int i = blockIdx.x * 256 + threadIdx.x;
    if (i < N_NODES) g_row_ptr[i] += g_partials[blockIdx.x];
}

// ---- CSR fill: one thread per edge ----
__global__ void fill_csr(const int* __restrict__ src, const int* __restrict__ dst, int E) {
    int e = blockIdx.x * blockDim.x + threadIdx.x;
    if (e >= E) return;
    int s = src[e], d = dst[e];
    int pos = g_row_ptr[d] + atomicAdd(&g_fill[d], 1);
    g_csr_src[pos] = s;
    g_csr_w[pos]   = g_dinv[s] * g_dinv[d];
}

// ---- pull one propagation layer: one wave (64 lanes = 64 dims) per dst node ----
__global__ void pull_layer(const float* __restrict__ h, float* __restrict__ hn) {
    int wid  = (blockIdx.x * blockDim.x + threadIdx.x) >> 6;
    int lane = threadIdx.x & 63;
    if (wid >= N_NODES) return;
    int beg = g_row_ptr[wid], end = g_row_ptr[wid + 1];
    float acc = 0.0f;
    for (int base = beg; base < end; base += 64) {
        int k = base + lane;
        int s = 0; float w = 0.0f;
        if (k < end) { s = g_csr_src[k]; w = g_csr_w[k]; }
        int cnt = min(64, end - base);
        for (int j = 0; j < cnt; ++j) {
            int   ss = __shfl(s, j);
            float ww = __shfl(w, j);
            acc += ww * h[(size_t)ss * DIM + lane];
        }
    }
    hn[(size_t)wid * DIM + lane] = acc;
}

// ---- gather sampled rows into per-sample accumulators: wave per (which,sample) ----
__global__ void gather_acc(const float* __restrict__ h,
                           const int* __restrict__ users, const int* __restrict__ pos,
                           const int* __restrict__ neg) {
    int wid  = (blockIdx.x * blockDim.x + threadIdx.x) >> 6;
    int lane = threadIdx.x & 63;
    if (wid >= 3 * BATCH) return;
    int which = wid / BATCH;
    int i     = wid - which * BATCH;
    const int* idx = (which == 0) ? users : ((which == 1) ? pos : neg);
    int node = idx[i];
    g_sums[(size_t)wid * DIM + lane] += h[(size_t)node * DIM + lane];
}

// ---- per-sample scores + reg partials, wave-64 reduce, atomic into 2 scalars ----
__global__ void score_reduce(const float* __restrict__ emb,
                             const int* __restrict__ users, const int* __restrict__ pos,
                             const int* __restrict__ neg) {
    int wid  = (blockIdx.x * blockDim.x + threadIdx.x) >> 6;
    int lane = threadIdx.x & 63;
    if (wid >= BATCH) return;
    float u = 0.25f * g_sums[(size_t)wid * DIM + lane];
    float p = 0.25f * g_sums[(size_t)(BATCH + wid) * DIM + lane];
    float n = 0.25f * g_sums[(size_t)(2 * BATCH + wid) * DIM + lane];
    float ps = u * p;
    float ns = u * n;
    float u0 = emb[(size_t)users[wid] * DIM + lane];
    float p0 = emb[(size_t)pos[wid]   * DIM + lane];
    float n0 = emb[(size_t)neg[wid]   * DIM + lane];
    float rg = u0 * u0 + p0 * p0 + n0 * n0;
    #pragma unroll
    for (int off = 32; off > 0; off >>= 1) {
        ps += __shfl_down(ps, off);
        ns += __shfl_down(ns, off);
        rg += __shfl_down(rg, off);
    }
    if (lane == 0) {
        float x  = ns - ps;
        float sp = fmaxf(x, 0.0f) + log1pf(expf(-fabsf(x)));  // stable softplus
        atomicAdd(&g_scalars[0], sp);
        atomicAdd(&g_scalars[1], rg);
    }
}

// ---- write the 3 outputs ----
__global__ void finalize(float* __restrict__ out) {
    float loss_emb = g_scalars[0] / (float)BATCH;
    float reg      = 0.5f * g_scalars[1] / (float)BATCH * REG_WEIGHT;
    out[0] = loss_emb + reg;
    out[1] = loss_emb;
    out[2] = reg;
}

extern "C" void kernel_launch(void* const* d_in, const int* in_sizes, int n_in,
                              void* d_out, int out_size, void* d_ws, size_t ws_size,
                              hipStream_t stream) {
    const float* emb   = (const float*)d_in[0];
    const int*   src   = (const int*)d_in[1];
    const int*   dst   = (const int*)d_in[2];
    const int*   users = (const int*)d_in[3];
    const int*   pos   = (const int*)d_in[4];
    const int*   neg   = (const int*)d_in[5];
    const int E = in_sizes[1];
    float* out = (float*)d_out;

    float* h_a;  hipGetSymbolAddress((void**)&h_a, HIP_SYMBOL(g_h));
    float* h_b = h_a + (size_t)N_NODES * DIM;

    zero_small<<<1024, 256, 0, stream>>>();
    count_deg<<<(E + 255) / 256, 256, 0, stream>>>(dst, E);
    make_dinv<<<(N_NODES + 255) / 256, 256, 0, stream>>>();

    scan_blocks<<<SCAN_BLOCKS, 256, 0, stream>>>();
    scan_partials<<<1, 64, 0, stream>>>(E);
    scan_add<<<SCAN_BLOCKS, 256, 0, stream>>>();
    fill_csr<<<(E + 255) / 256, 256, 0, stream>>>(src, dst, E);

    // layer 0 contribution (emb itself)
    gather_acc<<<(3 * BATCH * 64 + 255) / 256, 256, 0, stream>>>(emb, users, pos, neg);

    const float* hc = emb;
    float* bufs[2] = {h_a, h_b};
    for (int l = 0; l < NUM_LAYER; ++l) {
        float* hn = bufs[l & 1];
        pull_layer<<<(N_NODES * 64 + 255) / 256, 256, 0, stream>>>(hc, hn);
        gather_acc<<<(3 * BATCH * 64 + 255) / 256, 256, 0, stream>>>(hn, users, pos, neg);
        hc = hn;
    }

    score_reduce<<<(BATCH * 64 + 255) / 256, 256, 0, stream>>>(emb, users, pos, neg);
    finalize<<<1, 1, 0, stream>>>(out);
}

// Round 5
// 481.996 us; speedup vs baseline: 2.6761x; 1.2176x over previous
//
#include <hip/hip_runtime.h>
#include <math.h>

#define N_NODES 100000
#define DIM 64
#define NUM_LAYER 3
#define BATCH 4096
#define REG_WEIGHT 1e-4f
#define SCAN_BLOCKS ((N_NODES + 255) / 256)   // 391

// All scratch as device globals (ws_size unknown; this layout passed R2/R3).
__device__ float g_h[2][(size_t)N_NODES * DIM];    // ping-pong h buffers, 51.2 MB
__device__ float g_sums[(size_t)3 * BATCH * DIM];  // sampled-row accumulators
__device__ int   g_cnt[N_NODES];                   // in-degree counts
__device__ int   g_fill[N_NODES];                  // CSR fill cursors
__device__ int   g_row_ptr[N_NODES + 1];           // CSR row offsets (by dst)
__device__ int   g_partials[SCAN_BLOCKS];          // scan partials
__device__ float g_dinv[N_NODES];                  // deg^-0.5
__device__ int   g_csr_src[1280000];               // CSR column (src) indices
__device__ float g_csr_w[1280000];                 // CSR edge weights
__device__ float g_part_sp[BATCH];                 // per-wave softplus partials
__device__ float g_part_rg[BATCH];                 // per-wave reg partials

// ---- zero the small per-call state ----
__global__ void zero_small() {
    size_t i = (size_t)blockIdx.x * blockDim.x + threadIdx.x;
    size_t stride = (size_t)gridDim.x * blockDim.x;
    for (size_t k = i; k < (size_t)3 * BATCH * DIM; k += stride) g_sums[k] = 0.0f;
    for (size_t k = i; k < N_NODES; k += stride) { g_cnt[k] = 0; g_fill[k] = 0; }
}

// ---- degree count (int atomics) ----
__global__ void count_deg(const int* __restrict__ dst, int E) {
    int e = blockIdx.x * blockDim.x + threadIdx.x;
    if (e < E) atomicAdd(&g_cnt[dst[e]], 1);
}

// ---- dinv from counts ----
__global__ void make_dinv() {
    int v = blockIdx.x * blockDim.x + threadIdx.x;
    if (v < N_NODES) {
        int c = g_cnt[v];
        g_dinv[v] = (c > 0) ? rsqrtf((float)c) : 0.0f;
    }
}

// ---- exclusive scan of g_cnt -> g_row_ptr, 3 phases ----
__global__ void scan_blocks() {
    __shared__ int sm[256];
    int i = blockIdx.x * 256 + threadIdx.x;
    int v = (i < N_NODES) ? g_cnt[i] : 0;
    sm[threadIdx.x] = v;
    __syncthreads();
    for (int off = 1; off < 256; off <<= 1) {
        int t = (threadIdx.x >= off) ? sm[threadIdx.x - off] : 0;
        __syncthreads();
        sm[threadIdx.x] += t;
        __syncthreads();
    }
    if (i < N_NODES) g_row_ptr[i] = sm[threadIdx.x] - v;  // exclusive
    if (threadIdx.x == 255) g_partials[blockIdx.x] = sm[255];
}

// ---- single-block LDS scan of the 391 block partials ----
__global__ void scan_partials_fast(int E) {
    __shared__ int sm[512];
    int t = threadIdx.x;
    int v = (t < SCAN_BLOCKS) ? g_partials[t] : 0;
    sm[t] = v;
    __syncthreads();
    for (int off = 1; off < 512; off <<= 1) {
        int x = (t >= off) ? sm[t - off] : 0;
        __syncthreads();
        sm[t] += x;
        __syncthreads();
    }
    if (t < SCAN_BLOCKS) g_partials[t] = sm[t] - v;  // exclusive
    if (t == 0) g_row_ptr[N_NODES] = E;
}

__global__ void scan_add() {
    int i = blockIdx.x * 256 + threadIdx.x;
    if (i < N_NODES) g_row_ptr[i] += g_partials[blockIdx.x];
}

// ---- CSR fill: one thread per edge ----
__global__ void fill_csr(const int* __restrict__ src, const int* __restrict__ dst, int E) {
    int e = blockIdx.x * blockDim.x + threadIdx.x;
    if (e >= E) return;
    int s = src[e], d = dst[e];
    int pos = g_row_ptr[d] + atomicAdd(&g_fill[d], 1);
    g_csr_src[pos] = s;
    g_csr_w[pos]   = g_dinv[s] * g_dinv[d];
}

// ---- pull one propagation layer: one wave (64 lanes = 64 dims) per dst node ----
__global__ void pull_layer(const float* __restrict__ h, float* __restrict__ hn) {
    int wid  = (blockIdx.x * blockDim.x + threadIdx.x) >> 6;
    int lane = threadIdx.x & 63;
    if (wid >= N_NODES) return;
    int beg = g_row_ptr[wid], end = g_row_ptr[wid + 1];
    float acc = 0.0f;
    for (int base = beg; base < end; base += 64) {
        int k = base + lane;
        int s = 0; float w = 0.0f;
        if (k < end) { s = g_csr_src[k]; w = g_csr_w[k]; }
        int cnt = min(64, end - base);
        for (int j = 0; j < cnt; ++j) {
            int   ss = __shfl(s, j);
            float ww = __shfl(w, j);
            acc += ww * h[(size_t)ss * DIM + lane];
        }
    }
    hn[(size_t)wid * DIM + lane] = acc;
}

// ---- gather sampled rows into per-sample accumulators: wave per (which,sample) ----
__global__ void gather_acc(const float* __restrict__ h,
                           const int* __restrict__ users, const int* __restrict__ pos,
                           const int* __restrict__ neg) {
    int wid  = (blockIdx.x * blockDim.x + threadIdx.x) >> 6;
    int lane = threadIdx.x & 63;
    if (wid >= 3 * BATCH) return;
    int which = wid / BATCH;
    int i     = wid - which * BATCH;
    const int* idx = (which == 0) ? users : ((which == 1) ? pos : neg);
    int node = idx[i];
    g_sums[(size_t)wid * DIM + lane] += h[(size_t)node * DIM + lane];
}

// ---- per-sample scores + reg partials, wave-64 reduce, partials to arrays (NO atomics) ----
__global__ void score_reduce(const float* __restrict__ emb,
                             const int* __restrict__ users, const int* __restrict__ pos,
                             const int* __restrict__ neg) {
    int wid  = (blockIdx.x * blockDim.x + threadIdx.x) >> 6;
    int lane = threadIdx.x & 63;
    if (wid >= BATCH) return;
    float u = 0.25f * g_sums[(size_t)wid * DIM + lane];
    float p = 0.25f * g_sums[(size_t)(BATCH + wid) * DIM + lane];
    float n = 0.25f * g_sums[(size_t)(2 * BATCH + wid) * DIM + lane];
    float ps = u * p;
    float ns = u * n;
    float u0 = emb[(size_t)users[wid] * DIM + lane];
    float p0 = emb[(size_t)pos[wid]   * DIM + lane];
    float n0 = emb[(size_t)neg[wid]   * DIM + lane];
    float rg = u0 * u0 + p0 * p0 + n0 * n0;
    #pragma unroll
    for (int off = 32; off > 0; off >>= 1) {
        ps += __shfl_down(ps, off);
        ns += __shfl_down(ns, off);
        rg += __shfl_down(rg, off);
    }
    if (lane == 0) {
        float x  = ns - ps;
        float sp = fmaxf(x, 0.0f) + log1pf(expf(-fabsf(x)));  // stable softplus
        g_part_sp[wid] = sp;
        g_part_rg[wid] = rg;
    }
}

// ---- single-block final reduction over the 4096 per-wave partials ----
__global__ void final_reduce(float* __restrict__ out) {
    __shared__ float s_sp[256], s_rg[256];
    int t = threadIdx.x;
    float sp = 0.0f, rg = 0.0f;
    for (int i = t; i < BATCH; i += 256) { sp += g_part_sp[i]; rg += g_part_rg[i]; }
    s_sp[t] = sp; s_rg[t] = rg;
    __syncthreads();
    for (int off = 128; off > 0; off >>= 1) {
        if (t < off) { s_sp[t] += s_sp[t + off]; s_rg[t] += s_rg[t + off]; }
        __syncthreads();
    }
    if (t == 0) {
        float loss_emb = s_sp[0] / (float)BATCH;
        float reg      = 0.5f * s_rg[0] / (float)BATCH * REG_WEIGHT;
        out[0] = loss_emb + reg;
        out[1] = loss_emb;
        out[2] = reg;
    }
}

extern "C" void kernel_launch(void* const* d_in, const int* in_sizes, int n_in,
                              void* d_out, int out_size, void* d_ws, size_t ws_size,
                              hipStream_t stream) {
    const float* emb   = (const float*)d_in[0];
    const int*   src   = (const int*)d_in[1];
    const int*   dst   = (const int*)d_in[2];
    const int*   users = (const int*)d_in[3];
    const int*   pos   = (const int*)d_in[4];
    const int*   neg   = (const int*)d_in[5];
    const int E = in_sizes[1];
    float* out = (float*)d_out;

    float* h_a;  hipGetSymbolAddress((void**)&h_a, HIP_SYMBOL(g_h));
    float* h_b = h_a + (size_t)N_NODES * DIM;

    zero_small<<<1024, 256, 0, stream>>>();
    count_deg<<<(E + 255) / 256, 256, 0, stream>>>(dst, E);
    make_dinv<<<(N_NODES + 255) / 256, 256, 0, stream>>>();

    scan_blocks<<<SCAN_BLOCKS, 256, 0, stream>>>();
    scan_partials_fast<<<1, 512, 0, stream>>>(E);
    scan_add<<<SCAN_BLOCKS, 256, 0, stream>>>();
    fill_csr<<<(E + 255) / 256, 256, 0, stream>>>(src, dst, E);

    // layer 0 contribution (emb itself)
    gather_acc<<<(3 * BATCH * 64 + 255) / 256, 256, 0, stream>>>(emb, users, pos, neg);

    const float* hc = emb;
    float* bufs[2] = {h_a, h_b};
    for (int l = 0; l < NUM_LAYER; ++l) {
        float* hn = bufs[l & 1];
        pull_layer<<<(N_NODES * 64 + 255) / 256, 256, 0, stream>>>(hc, hn);
        gather_acc<<<(3 * BATCH * 64 + 255) / 256, 256, 0, stream>>>(hn, users, pos, neg);
        hc = hn;
    }

    score_reduce<<<(BATCH * 64 + 255) / 256, 256, 0, stream>>>(emb, users, pos, neg);
    final_reduce<<<1, 256, 0, stream>>>(out);
}

// Round 6
// 416.329 us; speedup vs baseline: 3.0981x; 1.1577x over previous
//
#include <hip/hip_runtime.h>
#include <hip/hip_bf16.h>
#include <math.h>

#define N_NODES 100000
#define DIM 64
#define NUM_LAYER 3
#define BATCH 4096
#define REG_WEIGHT 1e-4f
#define SCAN_BLOCKS ((N_NODES + 255) / 256)   // 391

// Scratch as device globals (ws_size unknown; this pattern passed R2/R3/R5).
__device__ __hip_bfloat16 g_hb[2][(size_t)N_NODES * DIM];  // bf16 ping-pong h, 2x12.8 MB
__device__ float g_sums[(size_t)3 * BATCH * DIM];  // sampled-row accumulators (f32)
__device__ int   g_cnt[N_NODES];                   // in-degree counts
__device__ int   g_fill[N_NODES];                  // CSR fill cursors
__device__ int   g_row_ptr[N_NODES + 1];           // CSR row offsets (by dst)
__device__ int   g_partials[SCAN_BLOCKS];          // scan partials
__device__ float g_dinv[N_NODES];                  // deg^-0.5
__device__ int   g_csr_src[1280000];               // CSR column (src) indices
__device__ float g_csr_w[1280000];                 // CSR edge weights
__device__ float g_part_sp[BATCH];                 // per-wave softplus partials
__device__ float g_part_rg[BATCH];                 // per-wave reg partials

// ---- zero the small per-call state ----
__global__ void zero_small() {
    size_t i = (size_t)blockIdx.x * blockDim.x + threadIdx.x;
    size_t stride = (size_t)gridDim.x * blockDim.x;
    for (size_t k = i; k < (size_t)3 * BATCH * DIM; k += stride) g_sums[k] = 0.0f;
    for (size_t k = i; k < N_NODES; k += stride) { g_cnt[k] = 0; g_fill[k] = 0; }
}

// ---- degree count (int atomics) ----
__global__ void count_deg(const int* __restrict__ dst, int E) {
    int e = blockIdx.x * blockDim.x + threadIdx.x;
    if (e < E) atomicAdd(&g_cnt[dst[e]], 1);
}

// ---- dinv from counts ----
__global__ void make_dinv() {
    int v = blockIdx.x * blockDim.x + threadIdx.x;
    if (v < N_NODES) {
        int c = g_cnt[v];
        g_dinv[v] = (c > 0) ? rsqrtf((float)c) : 0.0f;
    }
}

// ---- exclusive scan of g_cnt -> g_row_ptr, 3 phases ----
__global__ void scan_blocks() {
    __shared__ int sm[256];
    int i = blockIdx.x * 256 + threadIdx.x;
    int v = (i < N_NODES) ? g_cnt[i] : 0;
    sm[threadIdx.x] = v;
    __syncthreads();
    for (int off = 1; off < 256; off <<= 1) {
        int t = (threadIdx.x >= off) ? sm[threadIdx.x - off] : 0;
        __syncthreads();
        sm[threadIdx.x] += t;
        __syncthreads();
    }
    if (i < N_NODES) g_row_ptr[i] = sm[threadIdx.x] - v;  // exclusive
    if (threadIdx.x == 255) g_partials[blockIdx.x] = sm[255];
}

__global__ void scan_partials_fast(int E) {
    __shared__ int sm[512];
    int t = threadIdx.x;
    int v = (t < SCAN_BLOCKS) ? g_partials[t] : 0;
    sm[t] = v;
    __syncthreads();
    for (int off = 1; off < 512; off <<= 1) {
        int x = (t >= off) ? sm[t - off] : 0;
        __syncthreads();
        sm[t] += x;
        __syncthreads();
    }
    if (t < SCAN_BLOCKS) g_partials[t] = sm[t] - v;  // exclusive
    if (t == 0) g_row_ptr[N_NODES] = E;
}

__global__ void scan_add() {
    int i = blockIdx.x * 256 + threadIdx.x;
    if (i < N_NODES) g_row_ptr[i] += g_partials[blockIdx.x];
}

// ---- CSR fill: one thread per edge ----
__global__ void fill_csr(const int* __restrict__ src, const int* __restrict__ dst, int E) {
    int e = blockIdx.x * blockDim.x + threadIdx.x;
    if (e >= E) return;
    int s = src[e], d = dst[e];
    int pos = g_row_ptr[d] + atomicAdd(&g_fill[d], 1);
    g_csr_src[pos] = s;
    g_csr_w[pos]   = g_dinv[s] * g_dinv[d];
}

// ---- convert emb (f32) to bf16 buffer ----
__global__ void emb_to_bf16(const float* __restrict__ emb, __hip_bfloat16* __restrict__ hb) {
    size_t i = (size_t)blockIdx.x * blockDim.x + threadIdx.x;
    size_t stride = (size_t)gridDim.x * blockDim.x;
    for (size_t k = i; k < (size_t)N_NODES * DIM; k += stride)
        hb[k] = __float2bfloat16(emb[k]);
}

// ---- pull one propagation layer (bf16 in/out, f32 accumulate): wave per dst node ----
__global__ void pull_layer_bf16(const __hip_bfloat16* __restrict__ h,
                                __hip_bfloat16* __restrict__ hn) {
    int wid  = (blockIdx.x * blockDim.x + threadIdx.x) >> 6;
    int lane = threadIdx.x & 63;
    if (wid >= N_NODES) return;
    int beg = g_row_ptr[wid], end = g_row_ptr[wid + 1];
    float acc = 0.0f;
    for (int base = beg; base < end; base += 64) {
        int k = base + lane;
        int s = 0; float w = 0.0f;
        if (k < end) { s = g_csr_src[k]; w = g_csr_w[k]; }
        int cnt = min(64, end - base);
        for (int j = 0; j < cnt; ++j) {
            int   ss = __shfl(s, j);
            float ww = __shfl(w, j);
            acc += ww * __bfloat162float(h[(size_t)ss * DIM + lane]);
        }
    }
    hn[(size_t)wid * DIM + lane] = __float2bfloat16(acc);
}

// ---- final layer: pull ONLY the sampled rows, add straight into g_sums ----
__global__ void pull_sampled(const __hip_bfloat16* __restrict__ h,
                             const int* __restrict__ users, const int* __restrict__ pos,
                             const int* __restrict__ neg) {
    int wid  = (blockIdx.x * blockDim.x + threadIdx.x) >> 6;
    int lane = threadIdx.x & 63;
    if (wid >= 3 * BATCH) return;
    int which = wid / BATCH;
    int i     = wid - which * BATCH;
    const int* idx = (which == 0) ? users : ((which == 1) ? pos : neg);
    int node = idx[i];
    int beg = g_row_ptr[node], end = g_row_ptr[node + 1];
    float acc = 0.0f;
    for (int base = beg; base < end; base += 64) {
        int k = base + lane;
        int s = 0; float w = 0.0f;
        if (k < end) { s = g_csr_src[k]; w = g_csr_w[k]; }
        int cnt = min(64, end - base);
        for (int j = 0; j < cnt; ++j) {
            int   ss = __shfl(s, j);
            float ww = __shfl(w, j);
            acc += ww * __bfloat162float(h[(size_t)ss * DIM + lane]);
        }
    }
    g_sums[(size_t)wid * DIM + lane] += acc;  // wid owns this row; no atomics
}

// ---- gather sampled rows (f32 source: layer 0 = emb) ----
__global__ void gather_acc_f32(const float* __restrict__ h,
                               const int* __restrict__ users, const int* __restrict__ pos,
                               const int* __restrict__ neg) {
    int wid  = (blockIdx.x * blockDim.x + threadIdx.x) >> 6;
    int lane = threadIdx.x & 63;
    if (wid >= 3 * BATCH) return;
    int which = wid / BATCH;
    int i     = wid - which * BATCH;
    const int* idx = (which == 0) ? users : ((which == 1) ? pos : neg);
    int node = idx[i];
    g_sums[(size_t)wid * DIM + lane] += h[(size_t)node * DIM + lane];
}

// ---- gather sampled rows (bf16 source: layers 1,2) ----
__global__ void gather_acc_bf16(const __hip_bfloat16* __restrict__ h,
                                const int* __restrict__ users, const int* __restrict__ pos,
                                const int* __restrict__ neg) {
    int wid  = (blockIdx.x * blockDim.x + threadIdx.x) >> 6;
    int lane = threadIdx.x & 63;
    if (wid >= 3 * BATCH) return;
    int which = wid / BATCH;
    int i     = wid - which * BATCH;
    const int* idx = (which == 0) ? users : ((which == 1) ? pos : neg);
    int node = idx[i];
    g_sums[(size_t)wid * DIM + lane] += __bfloat162float(h[(size_t)node * DIM + lane]);
}

// ---- per-sample scores + reg partials, wave-64 reduce, partials to arrays (NO atomics) ----
__global__ void score_reduce(const float* __restrict__ emb,
                             const int* __restrict__ users, const int* __restrict__ pos,
                             const int* __restrict__ neg) {
    int wid  = (blockIdx.x * blockDim.x + threadIdx.x) >> 6;
    int lane = threadIdx.x & 63;
    if (wid >= BATCH) return;
    float u = 0.25f * g_sums[(size_t)wid * DIM + lane];
    float p = 0.25f * g_sums[(size_t)(BATCH + wid) * DIM + lane];
    float n = 0.25f * g_sums[(size_t)(2 * BATCH + wid) * DIM + lane];
    float ps = u * p;
    float ns = u * n;
    float u0 = emb[(size_t)users[wid] * DIM + lane];
    float p0 = emb[(size_t)pos[wid]   * DIM + lane];
    float n0 = emb[(size_t)neg[wid]   * DIM + lane];
    float rg = u0 * u0 + p0 * p0 + n0 * n0;
    #pragma unroll
    for (int off = 32; off > 0; off >>= 1) {
        ps += __shfl_down(ps, off);
        ns += __shfl_down(ns, off);
        rg += __shfl_down(rg, off);
    }
    if (lane == 0) {
        float x  = ns - ps;
        float sp = fmaxf(x, 0.0f) + log1pf(expf(-fabsf(x)));  // stable softplus
        g_part_sp[wid] = sp;
        g_part_rg[wid] = rg;
    }
}

// ---- single-block final reduction over the 4096 per-wave partials ----
__global__ void final_reduce(float* __restrict__ out) {
    __shared__ float s_sp[256], s_rg[256];
    int t = threadIdx.x;
    float sp = 0.0f, rg = 0.0f;
    for (int i = t; i < BATCH; i += 256) { sp += g_part_sp[i]; rg += g_part_rg[i]; }
    s_sp[t] = sp; s_rg[t] = rg;
    __syncthreads();
    for (int off = 128; off > 0; off >>= 1) {
        if (t < off) { s_sp[t] += s_sp[t + off]; s_rg[t] += s_rg[t + off]; }
        __syncthreads();
    }
    if (t == 0) {
        float loss_emb = s_sp[0] / (float)BATCH;
        float reg      = 0.5f * s_rg[0] / (float)BATCH * REG_WEIGHT;
        out[0] = loss_emb + reg;
        out[1] = loss_emb;
        out[2] = reg;
    }
}

extern "C" void kernel_launch(void* const* d_in, const int* in_sizes, int n_in,
                              void* d_out, int out_size, void* d_ws, size_t ws_size,
                              hipStream_t stream) {
    const float* emb   = (const float*)d_in[0];
    const int*   src   = (const int*)d_in[1];
    const int*   dst   = (const int*)d_in[2];
    const int*   users = (const int*)d_in[3];
    const int*   pos   = (const int*)d_in[4];
    const int*   neg   = (const int*)d_in[5];
    const int E = in_sizes[1];
    float* out = (float*)d_out;

    __hip_bfloat16* hb_a;  hipGetSymbolAddress((void**)&hb_a, HIP_SYMBOL(g_hb));
    __hip_bfloat16* hb_b = hb_a + (size_t)N_NODES * DIM;

    zero_small<<<1024, 256, 0, stream>>>();
    count_deg<<<(E + 255) / 256, 256, 0, stream>>>(dst, E);
    make_dinv<<<(N_NODES + 255) / 256, 256, 0, stream>>>();

    scan_blocks<<<SCAN_BLOCKS, 256, 0, stream>>>();
    scan_partials_fast<<<1, 512, 0, stream>>>(E);
    scan_add<<<SCAN_BLOCKS, 256, 0, stream>>>();
    fill_csr<<<(E + 255) / 256, 256, 0, stream>>>(src, dst, E);

    emb_to_bf16<<<2048, 256, 0, stream>>>(emb, hb_a);

    // layer 0 contribution (emb itself, f32)
    gather_acc_f32<<<(3 * BATCH * 64 + 255) / 256, 256, 0, stream>>>(emb, users, pos, neg);

    // layer 1: full pull (needed as input to layer 2)
    pull_layer_bf16<<<(N_NODES * 64 + 255) / 256, 256, 0, stream>>>(hb_a, hb_b);
    gather_acc_bf16<<<(3 * BATCH * 64 + 255) / 256, 256, 0, stream>>>(hb_b, users, pos, neg);

    // layer 2: full pull (needed as input to layer 3's sampled pull)
    pull_layer_bf16<<<(N_NODES * 64 + 255) / 256, 256, 0, stream>>>(hb_b, hb_a);
    gather_acc_bf16<<<(3 * BATCH * 64 + 255) / 256, 256, 0, stream>>>(hb_a, users, pos, neg);

    // layer 3: only the 3*BATCH sampled rows are ever read — pull just those
    pull_sampled<<<(3 * BATCH * 64 + 255) / 256, 256, 0, stream>>>(hb_a, users, pos, neg);

    score_reduce<<<(BATCH * 64 + 255) / 256, 256, 0, stream>>>(emb, users, pos, neg);
    final_reduce<<<1, 256, 0, stream>>>(out);
}

// Round 7
// 325.118 us; speedup vs baseline: 3.9673x; 1.2805x over previous
//
#include <hip/hip_runtime.h>
#include <hip/hip_bf16.h>
#include <hip/hip_fp8.h>
#include <math.h>

#define N_NODES 100000
#define DIM 64
#define NUM_LAYER 3
#define BATCH 4096
#define REG_WEIGHT 1e-4f
#define SCAN_BLOCKS ((N_NODES + 255) / 256)   // 391
#define H_SCALE 64.0f
#define H_INV_SCALE (1.0f / 64.0f)

// Scratch as device globals (ws_size unknown; this pattern passed R2/R3/R5/R6).
__device__ unsigned char g_hf8[2][(size_t)N_NODES * DIM]; // fp8 ping-pong h (scaled by H_SCALE)
__device__ float g_sums[(size_t)3 * BATCH * DIM];  // sampled-row accumulators (f32)
__device__ int   g_cnt[N_NODES];                   // in-degree counts
__device__ int   g_fill[N_NODES];                  // CSR fill cursors
__device__ int   g_row_ptr[N_NODES + 1];           // CSR row offsets (by dst)
__device__ int   g_partials[SCAN_BLOCKS];          // scan partials
__device__ float g_dinv[N_NODES];                  // deg^-0.5
__device__ int2  g_csr[1280000];                   // packed (src, w-as-bits) per edge
__device__ float g_part_sp[BATCH];                 // per-wave softplus partials
__device__ float g_part_rg[BATCH];                 // per-wave reg partials

__device__ inline float fp8_to_f32(unsigned char v) {
    __hip_fp8_e4m3 t; t.__x = (__hip_fp8_storage_t)v; return (float)t;
}
__device__ inline unsigned char f32_to_fp8(float f) {
    __hip_fp8_e4m3 t(f); return (unsigned char)t.__x;
}

// ---- zero the small per-call state ----
__global__ void zero_small() {
    size_t i = (size_t)blockIdx.x * blockDim.x + threadIdx.x;
    size_t stride = (size_t)gridDim.x * blockDim.x;
    for (size_t k = i; k < (size_t)3 * BATCH * DIM; k += stride) g_sums[k] = 0.0f;
    for (size_t k = i; k < N_NODES; k += stride) { g_cnt[k] = 0; g_fill[k] = 0; }
}

// ---- degree count (int atomics) ----
__global__ void count_deg(const int* __restrict__ dst, int E) {
    int e = blockIdx.x * blockDim.x + threadIdx.x;
    if (e < E) atomicAdd(&g_cnt[dst[e]], 1);
}

// ---- dinv from counts ----
__global__ void make_dinv() {
    int v = blockIdx.x * blockDim.x + threadIdx.x;
    if (v < N_NODES) {
        int c = g_cnt[v];
        g_dinv[v] = (c > 0) ? rsqrtf((float)c) : 0.0f;
    }
}

// ---- exclusive scan of g_cnt -> g_row_ptr, 3 phases ----
__global__ void scan_blocks() {
    __shared__ int sm[256];
    int i = blockIdx.x * 256 + threadIdx.x;
    int v = (i < N_NODES) ? g_cnt[i] : 0;
    sm[threadIdx.x] = v;
    __syncthreads();
    for (int off = 1; off < 256; off <<= 1) {
        int t = (threadIdx.x >= off) ? sm[threadIdx.x - off] : 0;
        __syncthreads();
        sm[threadIdx.x] += t;
        __syncthreads();
    }
    if (i < N_NODES) g_row_ptr[i] = sm[threadIdx.x] - v;  // exclusive
    if (threadIdx.x == 255) g_partials[blockIdx.x] = sm[255];
}

__global__ void scan_partials_fast(int E) {
    __shared__ int sm[512];
    int t = threadIdx.x;
    int v = (t < SCAN_BLOCKS) ? g_partials[t] : 0;
    sm[t] = v;
    __syncthreads();
    for (int off = 1; off < 512; off <<= 1) {
        int x = (t >= off) ? sm[t - off] : 0;
        __syncthreads();
        sm[t] += x;
        __syncthreads();
    }
    if (t < SCAN_BLOCKS) g_partials[t] = sm[t] - v;  // exclusive
    if (t == 0) g_row_ptr[N_NODES] = E;
}

__global__ void scan_add() {
    int i = blockIdx.x * 256 + threadIdx.x;
    if (i < N_NODES) g_row_ptr[i] += g_partials[blockIdx.x];
}

// ---- CSR fill: one thread per edge, single packed 8B store ----
__global__ void fill_csr(const int* __restrict__ src, const int* __restrict__ dst, int E) {
    int e = blockIdx.x * blockDim.x + threadIdx.x;
    if (e >= E) return;
    int s = src[e], d = dst[e];
    int pos = g_row_ptr[d] + atomicAdd(&g_fill[d], 1);
    float w = g_dinv[s] * g_dinv[d];
    g_csr[pos] = make_int2(s, __float_as_int(w));
}

// ---- convert emb (f32) to scaled fp8 ----
__global__ void emb_to_fp8(const float* __restrict__ emb, unsigned char* __restrict__ hf) {
    size_t i = (size_t)blockIdx.x * blockDim.x + threadIdx.x;
    size_t stride = (size_t)gridDim.x * blockDim.x;
    for (size_t k = i; k < (size_t)N_NODES * DIM; k += stride)
        hf[k] = f32_to_fp8(emb[k] * H_SCALE);
}

// ---- pull one layer (fp8 in/out scaled domain, f32 acc): wave per dst, 4-way unroll ----
__global__ void pull_layer_fp8(const unsigned char* __restrict__ h,
                               unsigned char* __restrict__ hn) {
    int wid  = (blockIdx.x * blockDim.x + threadIdx.x) >> 6;
    int lane = threadIdx.x & 63;
    if (wid >= N_NODES) return;
    int beg = g_row_ptr[wid], end = g_row_ptr[wid + 1];
    float acc = 0.0f;
    for (int base = beg; base < end; base += 64) {
        int k = base + lane;
        int s = 0; float w = 0.0f;
        if (k < end) { int2 ew = g_csr[k]; s = ew.x; w = __int_as_float(ew.y); }
        int cnt = min(64, end - base);
        int j = 0;
        for (; j + 4 <= cnt; j += 4) {   // 4 independent gathers in flight
            int   s0 = __shfl(s, j),     s1 = __shfl(s, j + 1);
            int   s2 = __shfl(s, j + 2), s3 = __shfl(s, j + 3);
            float w0 = __shfl(w, j),     w1 = __shfl(w, j + 1);
            float w2 = __shfl(w, j + 2), w3 = __shfl(w, j + 3);
            float h0 = fp8_to_f32(h[(size_t)s0 * DIM + lane]);
            float h1 = fp8_to_f32(h[(size_t)s1 * DIM + lane]);
            float h2 = fp8_to_f32(h[(size_t)s2 * DIM + lane]);
            float h3 = fp8_to_f32(h[(size_t)s3 * DIM + lane]);
            acc = fmaf(w0, h0, acc); acc = fmaf(w1, h1, acc);
            acc = fmaf(w2, h2, acc); acc = fmaf(w3, h3, acc);
        }
        for (; j < cnt; ++j) {
            int   ss = __shfl(s, j);
            float ww = __shfl(w, j);
            acc = fmaf(ww, fp8_to_f32(h[(size_t)ss * DIM + lane]), acc);
        }
    }
    hn[(size_t)wid * DIM + lane] = f32_to_fp8(acc);
}

// ---- final layer: pull ONLY the sampled rows, add into g_sums (unscale here) ----
__global__ void pull_sampled(const unsigned char* __restrict__ h,
                             const int* __restrict__ users, const int* __restrict__ pos,
                             const int* __restrict__ neg) {
    int wid  = (blockIdx.x * blockDim.x + threadIdx.x) >> 6;
    int lane = threadIdx.x & 63;
    if (wid >= 3 * BATCH) return;
    int which = wid / BATCH;
    int i     = wid - which * BATCH;
    const int* idx = (which == 0) ? users : ((which == 1) ? pos : neg);
    int node = idx[i];
    int beg = g_row_ptr[node], end = g_row_ptr[node + 1];
    float acc = 0.0f;
    for (int base = beg; base < end; base += 64) {
        int k = base + lane;
        int s = 0; float w = 0.0f;
        if (k < end) { int2 ew = g_csr[k]; s = ew.x; w = __int_as_float(ew.y); }
        int cnt = min(64, end - base);
        int j = 0;
        for (; j + 4 <= cnt; j += 4) {
            int   s0 = __shfl(s, j),     s1 = __shfl(s, j + 1);
            int   s2 = __shfl(s, j + 2), s3 = __shfl(s, j + 3);
            float w0 = __shfl(w, j),     w1 = __shfl(w, j + 1);
            float w2 = __shfl(w, j + 2), w3 = __shfl(w, j + 3);
            float h0 = fp8_to_f32(h[(size_t)s0 * DIM + lane]);
            float h1 = fp8_to_f32(h[(size_t)s1 * DIM + lane]);
            float h2 = fp8_to_f32(h[(size_t)s2 * DIM + lane]);
            float h3 = fp8_to_f32(h[(size_t)s3 * DIM + lane]);
            acc = fmaf(w0, h0, acc); acc = fmaf(w1, h1, acc);
            acc = fmaf(w2, h2, acc); acc = fmaf(w3, h3, acc);
        }
        for (; j < cnt; ++j) {
            int   ss = __shfl(s, j);
            float ww = __shfl(w, j);
            acc = fmaf(ww, fp8_to_f32(h[(size_t)ss * DIM + lane]), acc);
        }
    }
    g_sums[(size_t)wid * DIM + lane] += acc * H_INV_SCALE;  // wid owns row; no atomics
}

// ---- gather sampled rows (f32 source: layer 0 = emb) ----
__global__ void gather_acc_f32(const float* __restrict__ h,
                               const int* __restrict__ users, const int* __restrict__ pos,
                               const int* __restrict__ neg) {
    int wid  = (blockIdx.x * blockDim.x + threadIdx.x) >> 6;
    int lane = threadIdx.x & 63;
    if (wid >= 3 * BATCH) return;
    int which = wid / BATCH;
    int i     = wid - which * BATCH;
    const int* idx = (which == 0) ? users : ((which == 1) ? pos : neg);
    int node = idx[i];
    g_sums[(size_t)wid * DIM + lane] += h[(size_t)node * DIM + lane];
}

// ---- gather sampled rows (fp8 scaled source: layers 1,2) ----
__global__ void gather_acc_fp8(const unsigned char* __restrict__ h,
                               const int* __restrict__ users, const int* __restrict__ pos,
                               const int* __restrict__ neg) {
    int wid  = (blockIdx.x * blockDim.x + threadIdx.x) >> 6;
    int lane = threadIdx.x & 63;
    if (wid >= 3 * BATCH) return;
    int which = wid / BATCH;
    int i     = wid - which * BATCH;
    const int* idx = (which == 0) ? users : ((which == 1) ? pos : neg);
    int node = idx[i];
    g_sums[(size_t)wid * DIM + lane] += fp8_to_f32(h[(size_t)node * DIM + lane]) * H_INV_SCALE;
}

// ---- per-sample scores + reg partials, wave-64 reduce, partials to arrays (NO atomics) ----
__global__ void score_reduce(const float* __restrict__ emb,
                             const int* __restrict__ users, const int* __restrict__ pos,
                             const int* __restrict__ neg) {
    int wid  = (blockIdx.x * blockDim.x + threadIdx.x) >> 6;
    int lane = threadIdx.x & 63;
    if (wid >= BATCH) return;
    float u = 0.25f * g_sums[(size_t)wid * DIM + lane];
    float p = 0.25f * g_sums[(size_t)(BATCH + wid) * DIM + lane];
    float n = 0.25f * g_sums[(size_t)(2 * BATCH + wid) * DIM + lane];
    float ps = u * p;
    float ns = u * n;
    float u0 = emb[(size_t)users[wid] * DIM + lane];
    float p0 = emb[(size_t)pos[wid]   * DIM + lane];
    float n0 = emb[(size_t)neg[wid]   * DIM + lane];
    float rg = u0 * u0 + p0 * p0 + n0 * n0;
    #pragma unroll
    for (int off = 32; off > 0; off >>= 1) {
        ps += __shfl_down(ps, off);
        ns += __shfl_down(ns, off);
        rg += __shfl_down(rg, off);
    }
    if (lane == 0) {
        float x  = ns - ps;
        float sp = fmaxf(x, 0.0f) + log1pf(expf(-fabsf(x)));  // stable softplus
        g_part_sp[wid] = sp;
        g_part_rg[wid] = rg;
    }
}

// ---- single-block final reduction over the 4096 per-wave partials ----
__global__ void final_reduce(float* __restrict__ out) {
    __shared__ float s_sp[256], s_rg[256];
    int t = threadIdx.x;
    float sp = 0.0f, rg = 0.0f;
    for (int i = t; i < BATCH; i += 256) { sp += g_part_sp[i]; rg += g_part_rg[i]; }
    s_sp[t] = sp; s_rg[t] = rg;
    __syncthreads();
    for (int off = 128; off > 0; off >>= 1) {
        if (t < off) { s_sp[t] += s_sp[t + off]; s_rg[t] += s_rg[t + off]; }
        __syncthreads();
    }
    if (t == 0) {
        float loss_emb = s_sp[0] / (float)BATCH;
        float reg      = 0.5f * s_rg[0] / (float)BATCH * REG_WEIGHT;
        out[0] = loss_emb + reg;
        out[1] = loss_emb;
        out[2] = reg;
    }
}

extern "C" void kernel_launch(void* const* d_in, const int* in_sizes, int n_in,
                              void* d_out, int out_size, void* d_ws, size_t ws_size,
                              hipStream_t stream) {
    const float* emb   = (const float*)d_in[0];
    const int*   src   = (const int*)d_in[1];
    const int*   dst   = (const int*)d_in[2];
    const int*   users = (const int*)d_in[3];
    const int*   pos   = (const int*)d_in[4];
    const int*   neg   = (const int*)d_in[5];
    const int E = in_sizes[1];
    float* out = (float*)d_out;

    unsigned char* hf_a;  hipGetSymbolAddress((void**)&hf_a, HIP_SYMBOL(g_hf8));
    unsigned char* hf_b = hf_a + (size_t)N_NODES * DIM;

    zero_small<<<1024, 256, 0, stream>>>();
    count_deg<<<(E + 255) / 256, 256, 0, stream>>>(dst, E);
    make_dinv<<<(N_NODES + 255) / 256, 256, 0, stream>>>();

    scan_blocks<<<SCAN_BLOCKS, 256, 0, stream>>>();
    scan_partials_fast<<<1, 512, 0, stream>>>(E);
    scan_add<<<SCAN_BLOCKS, 256, 0, stream>>>();
    fill_csr<<<(E + 255) / 256, 256, 0, stream>>>(src, dst, E);

    emb_to_fp8<<<2048, 256, 0, stream>>>(emb, hf_a);

    // layer 0 contribution (emb itself, f32)
    gather_acc_f32<<<(3 * BATCH * 64 + 255) / 256, 256, 0, stream>>>(emb, users, pos, neg);

    // layer 1: full pull (needed as input to layer 2)
    pull_layer_fp8<<<(N_NODES * 64 + 255) / 256, 256, 0, stream>>>(hf_a, hf_b);
    gather_acc_fp8<<<(3 * BATCH * 64 + 255) / 256, 256, 0, stream>>>(hf_b, users, pos, neg);

    // layer 2: full pull (needed as input to layer 3's sampled pull)
    pull_layer_fp8<<<(N_NODES * 64 + 255) / 256, 256, 0, stream>>>(hf_b, hf_a);
    gather_acc_fp8<<<(3 * BATCH * 64 + 255) / 256, 256, 0, stream>>>(hf_a, users, pos, neg);

    // layer 3: only the 3*BATCH sampled rows are ever read — pull just those
    pull_sampled<<<(3 * BATCH * 64 + 255) / 256, 256, 0, stream>>>(hf_a, users, pos, neg);

    score_reduce<<<(BATCH * 64 + 255) / 256, 256, 0, stream>>>(emb, users, pos, neg);
    final_reduce<<<1, 256, 0, stream>>>(out);
}